// Round 10
// baseline (1551.583 us; speedup 1.0000x reference)
//
#include <hip/hip_runtime.h>
#include <hip/hip_bf16.h>

// Mamba4Rec fused forward. B=1024, L=200, D=64, DI=128, N=32, K=4, R=4, F=256.
constexpr int Bn = 1024, Ln = 200, Dm = 64, DI = 128, Fh = 256;

#define DEVFN __device__ __forceinline__

DEVFN float silu_(float x){ return x / (1.f + __expf(-x)); }
DEVFN float softplus_(float x){ return x > 20.f ? x : log1pf(__expf(x)); }
DEVFN float gelu_tanh_(float x){
  float c = 0.7978845608028654f * (x + 0.044715f * x * x * x);
  float e = __expf(2.f * c);
  float th = 1.f - 2.f / (e + 1.f);
  return 0.5f * x * (1.f + th);
}
DEVFN float wave64_sum(float v){
  #pragma unroll
  for (int off = 32; off; off >>= 1) v += __shfl_xor(v, off, 64);
  return v;
}
DEVFN unsigned short f2b(float f){           // f32 -> bf16 RNE
  unsigned int u = __float_as_uint(f);
  return (unsigned short)((u + 0x7fffu + ((u >> 16) & 1u)) >> 16);
}
DEVFN float b2f(unsigned short h){ return __uint_as_float(((unsigned int)h) << 16); }

// ============ K1: embed + LN + in_proj -> xc (bf16), z (bf16) ============
// grid 1024*5, 256 threads; thread = in_proj output row (64 stationary VGPRs).
// PLAIN launch_bounds: r3-kA measured config that yields ~132 VGPR, no spills.
__global__ __launch_bounds__(256)
void k1_embed_inproj(
    const int* __restrict__ ids, const float* __restrict__ emb,
    const float* __restrict__ lnw, const float* __restrict__ lnb,
    const float* __restrict__ ipw,
    unsigned short* __restrict__ xc, unsigned short* __restrict__ zy)
{
  __shared__ float xls[8][Dm];
  const int blk = blockIdx.x, b = blk / 5, t0 = (blk % 5) * 40;
  const int tid = threadIdx.x, wv = tid >> 6, ln = tid & 63;
  float wip[64];
  { const float4* p = (const float4*)(ipw + tid * Dm);
    #pragma unroll
    for (int k = 0; k < 16; k++) ((float4*)wip)[k] = p[k]; }
  const float lw = lnw[ln], lb = lnb[ln];
  const int* idb = ids + b * Ln;

  for (int sub = 0; sub < 5; sub++) {
    const int tt0 = t0 + sub * 8;
    #pragma unroll
    for (int s = 0; s < 2; s++) {
      int i = wv + 4 * s;
      float v = emb[(long)idb[tt0 + i] * Dm + ln];
      float mu  = wave64_sum(v) * (1.f / 64.f);
      float dv  = v - mu;
      float var = wave64_sum(dv * dv) * (1.f / 64.f);
      xls[i][ln] = dv * rsqrtf(var + 1e-12f) * lw + lb;
    }
    __syncthreads();
    #pragma unroll
    for (int i = 0; i < 8; i++) {
      const float4* xp = (const float4*)xls[i];
      float acc = 0.f;
      #pragma unroll
      for (int k = 0; k < 16; k++) {
        float4 x = xp[k];
        acc += wip[4*k+0]*x.x + wip[4*k+1]*x.y + wip[4*k+2]*x.z + wip[4*k+3]*x.w;
      }
      long idx = ((long)b * Ln + tt0 + i) * DI;
      unsigned short hv = f2b(acc);
      if (tid < DI) xc[idx + tid] = hv;
      else          zy[idx + tid - DI] = hv;
    }
    __syncthreads();
  }
}

// ============ K2: conv + SiLU + x_proj + dt_proj + scan + gate -> y (bf16, over z) ============
// grid 1024 (one block per sequence), 256 threads, ~27.5 KB LDS.
// PLAIN launch_bounds (no min-waves constraint): let allocator keep wxp/A/h resident.
__global__ __launch_bounds__(256)
void k2_conv_scan(
    const unsigned short* __restrict__ xc, unsigned short* __restrict__ zy,
    const float* __restrict__ cw, const float* __restrict__ cb,
    const float* __restrict__ xpw, const float* __restrict__ dtw, const float* __restrict__ dtb,
    const float* __restrict__ A_log, const float* __restrict__ Dp_g)
{
  constexpr int T = 8;
  __shared__ float xct[T + 3][DI];        // conv ring, rows 0..2 halo
  __shared__ float xs_s[T][132];
  __shared__ unsigned short z_s[T][DI];
  __shared__ unsigned short y_s[T][DI];
  __shared__ float psum[4][64 * 9];       // pitch 9: gcd(9,32)=1, conflict-free
  __shared__ float bc_s[T][68];
  __shared__ float dtlo_s[T][4];
  __shared__ float xpw_ext[4][DI];

  const int b = blockIdx.x, tid = threadIdx.x;
  const int wv = tid >> 6, ln = tid & 63;

  float wxp[32];
  { const float4* p = (const float4*)(xpw + ln * DI + wv * 32);
    #pragma unroll
    for (int k = 0; k < 8; k++) ((float4*)wxp)[k] = p[k]; }
  const int cd = tid & (DI - 1);
  const float4 cwv = *(const float4*)(cw + cd * 4);
  const float cbv = cb[cd];
  const int sd = tid >> 1, hf = tid & 1;
  const float4 dtwv = *(const float4*)(dtw + sd * 4);
  const float dtbv = dtb[sd], Dpv = Dp_g[sd];
  float A[16];
  { const float4* p = (const float4*)(A_log + sd * 32 + hf * 16);
    #pragma unroll
    for (int k = 0; k < 4; k++) {
      float4 v = p[k];
      A[4*k+0] = -__expf(v.x); A[4*k+1] = -__expf(v.y);
      A[4*k+2] = -__expf(v.z); A[4*k+3] = -__expf(v.w);
    } }
  float h[16];
  #pragma unroll
  for (int k = 0; k < 16; k++) h[k] = 0.f;

  for (int i = tid; i < 4 * DI; i += 256) xpw_ext[i >> 7][i & 127] = xpw[64 * DI + i];
  for (int i = tid; i < 3 * DI; i += 256) xct[i >> 7][i & 127] = 0.f;
  __syncthreads();

  for (int tile = 0; tile < 25; ++tile) {
    const int t0 = tile * T;
    const long gbase = ((long)b * Ln + t0) * DI;
    // ---- stage xc (cvt->f32 ring) and z (raw bf16) ----
    {
      ushort4 xv = ((const ushort4*)(xc + gbase))[tid];
      ushort4 zv = ((const ushort4*)(zy + gbase))[tid];
      int row = tid >> 5, col = (tid & 31) * 4;
      xct[3 + row][col + 0] = b2f(xv.x); xct[3 + row][col + 1] = b2f(xv.y);
      xct[3 + row][col + 2] = b2f(xv.z); xct[3 + row][col + 3] = b2f(xv.w);
      ((ushort4*)z_s)[tid] = zv;
    }
    __syncthreads();
    // ---- conv + SiLU ----
    #pragma unroll
    for (int s = 0; s < 4; s++) {
      int tt = (tid >> 7) + 2 * s;
      float v = cbv + cwv.x * xct[tt + 0][cd] + cwv.y * xct[tt + 1][cd]
                    + cwv.z * xct[tt + 2][cd] + cwv.w * xct[tt + 3][cd];
      xs_s[tt][cd] = silu_(v);
    }
    __syncthreads();
    // ---- x_proj: rows 0..63 K-split by wave; rows 64..67 full-K by 32 threads ----
    #pragma unroll
    for (int t = 0; t < T; t++) {
      const float4* xr = (const float4*)(&xs_s[t][wv * 32]);
      float a = 0.f;
      #pragma unroll
      for (int k = 0; k < 8; k++) {
        float4 x = xr[k];
        a += wxp[4*k+0]*x.x + wxp[4*k+1]*x.y + wxp[4*k+2]*x.z + wxp[4*k+3]*x.w;
      }
      psum[wv][ln * 9 + t] = a;
    }
    if (tid < 32) {
      int j = tid >> 3, t = tid & 7;
      const float4* wr = (const float4*)xpw_ext[j];
      const float4* xr = (const float4*)(&xs_s[t][0]);
      float a = 0.f;
      #pragma unroll
      for (int k = 0; k < 32; k++) {
        float4 w4 = wr[k]; float4 x = xr[k];
        a += w4.x*x.x + w4.y*x.y + w4.z*x.z + w4.w*x.w;
      }
      bc_s[t][60 + j] = a;
    }
    __syncthreads();
    // ---- reduce K-split partials ----
    #pragma unroll
    for (int s = 0; s < 2; s++) {
      int o = tid + 256 * s;
      int j = o >> 3, t = o & 7;
      float sum = psum[0][j*9+t] + psum[1][j*9+t] + psum[2][j*9+t] + psum[3][j*9+t];
      if (j < 4) dtlo_s[t][j] = sum;
      else       bc_s[t][j - 4] = sum;
    }
    __syncthreads();
    // ---- scan ----
    for (int t = 0; t < T; t++) {
      float4 dl = *(const float4*)dtlo_s[t];
      float dtv = softplus_(dtwv.x*dl.x + dtwv.y*dl.y + dtwv.z*dl.z + dtwv.w*dl.w + dtbv);
      float xsv = xs_s[t][sd];
      float zv  = b2f(z_s[t][sd]);
      float du  = dtv * xsv;
      const float4* bp = (const float4*)(&bc_s[t][hf * 16]);
      const float4* cp = (const float4*)(&bc_s[t][32 + hf * 16]);
      float y = 0.f;
      #pragma unroll
      for (int k = 0; k < 4; k++) {
        float4 Bv = bp[k], Cv = cp[k];
        float h0 = __expf(dtv*A[4*k+0]) * h[4*k+0] + du * Bv.x; h[4*k+0] = h0; y += h0 * Cv.x;
        float h1 = __expf(dtv*A[4*k+1]) * h[4*k+1] + du * Bv.y; h[4*k+1] = h1; y += h1 * Cv.y;
        float h2 = __expf(dtv*A[4*k+2]) * h[4*k+2] + du * Bv.z; h[4*k+2] = h2; y += h2 * Cv.z;
        float h3 = __expf(dtv*A[4*k+3]) * h[4*k+3] + du * Bv.w; h[4*k+3] = h3; y += h3 * Cv.w;
      }
      float yo = y + __shfl_xor(y, 1, 64);
      if (hf == 0)
        y_s[t][sd] = f2b((yo + Dpv * xsv) * silu_(zv));
    }
    __syncthreads();
    // ---- dump y over z; ring shift ----
    ((ushort4*)(zy + gbase))[tid] = ((ushort4*)y_s)[tid];
    for (int i = tid; i < 3 * DI; i += 256)
      xct[i >> 7][i & 127] = xct[8 + (i >> 7)][i & 127];
    __syncthreads();
  }
}

// ============ K3: out_proj + LN + FFN(GELU) + LN -> out ============
// grid 1024, 512 threads; stationary 80 VGPR/thread; 8 tokens per iter.
// PLAIN launch_bounds: allocator free to keep opp/w1h/w2p resident.
__global__ __launch_bounds__(512)
void k3_out_ffn(
    const unsigned short* __restrict__ y_g, const float* __restrict__ opw,
    const float* __restrict__ mlnw, const float* __restrict__ mlnb,
    const float* __restrict__ w1, const float* __restrict__ b1,
    const float* __restrict__ w2, const float* __restrict__ b2,
    const float* __restrict__ flnw, const float* __restrict__ flnb,
    float* __restrict__ out)
{
  __shared__ float y8[8][DI];          // 4 KB
  __shared__ float psum[4096];         // 16 KB (union: op / ffn1 / ffn2)
  __shared__ float hid8[8][Dm];        // 2 KB
  __shared__ float f4s[8 * Fh];        // 8 KB
  __shared__ float b1_s[Fh];           // 1 KB
  const int b = blockIdx.x, tid = threadIdx.x;
  const int u = tid >> 6, ln = tid & 63;   // 8 waves

  float opp[16], w1h[32], w2p[32];
  { const float4* p = (const float4*)(opw + ln * DI + u * 16);
    #pragma unroll
    for (int k = 0; k < 4; k++) ((float4*)opp)[k] = p[k];
    const float4* p1 = (const float4*)(w1 + (ln + (u & 3) * 64) * Dm + (u >> 2) * 32);
    #pragma unroll
    for (int k = 0; k < 8; k++) ((float4*)w1h)[k] = p1[k];
    const float4* p2 = (const float4*)(w2 + ln * Fh + u * 32);
    #pragma unroll
    for (int k = 0; k < 8; k++) ((float4*)w2p)[k] = p2[k]; }
  for (int i = tid; i < Fh; i += 512) b1_s[i] = b1[i];
  const float b2v = b2[ln];
  const float mw = mlnw[ln], mb = mlnb[ln], fw = flnw[ln], fb = flnb[ln];
  const int h2 = u >> 2, rrow = ln + (u & 3) * 64;

  for (int it = 0; it < 25; ++it) {
    const int t0 = it * 8;
    {
      ushort4 yv = ((const ushort4*)(y_g + ((long)b * Ln + t0) * DI))[tid];
      int row = tid >> 5, col = (tid & 31) * 4;
      y8[row][col + 0] = b2f(yv.x); y8[row][col + 1] = b2f(yv.y);
      y8[row][col + 2] = b2f(yv.z); y8[row][col + 3] = b2f(yv.w);
    }
    __syncthreads();
    // ---- out_proj (K-split 8x16) ----
    #pragma unroll
    for (int t = 0; t < 8; t++) {
      const float4* yp = (const float4*)(&y8[t][u * 16]);
      float acc = 0.f;
      #pragma unroll
      for (int k = 0; k < 4; k++) {
        float4 y = yp[k];
        acc += opp[4*k+0]*y.x + opp[4*k+1]*y.y + opp[4*k+2]*y.z + opp[4*k+3]*y.w;
      }
      psum[u * 512 + t * 64 + ln] = acc;
    }
    __syncthreads();
    {   // wave u owns token u: reduce + LN
      float m = 0.f;
      #pragma unroll
      for (int v = 0; v < 8; v++) m += psum[v * 512 + u * 64 + ln];
      float mu  = wave64_sum(m) * (1.f / 64.f);
      float dv  = m - mu;
      float var = wave64_sum(dv * dv) * (1.f / 64.f);
      hid8[u][ln] = dv * rsqrtf(var + 1e-12f) * mw + mb;
    }
    __syncthreads();
    // ---- ffn1 (K-halves of 32) ----
    #pragma unroll
    for (int t = 0; t < 8; t++) {
      const float4* hp = (const float4*)(&hid8[t][h2 * 32]);
      float acc = 0.f;
      #pragma unroll
      for (int k = 0; k < 8; k++) {
        float4 hv = hp[k];
        acc += w1h[4*k+0]*hv.x + w1h[4*k+1]*hv.y + w1h[4*k+2]*hv.z + w1h[4*k+3]*hv.w;
      }
      psum[h2 * 2048 + t * 256 + rrow] = acc;
    }
    __syncthreads();
    #pragma unroll
    for (int s = 0; s < 4; s++) {
      int o = tid + 512 * s;
      int t = o >> 8, r = o & 255;
      float v = b1_s[r] + psum[t * 256 + r] + psum[2048 + t * 256 + r];
      f4s[t * 256 + r] = gelu_tanh_(v);
    }
    __syncthreads();
    // ---- ffn2 (K-split 8x32) ----
    #pragma unroll
    for (int t = 0; t < 8; t++) {
      const float4* fp = (const float4*)(&f4s[t * 256 + u * 32]);
      float acc = 0.f;
      #pragma unroll
      for (int k = 0; k < 8; k++) {
        float4 fv = fp[k];
        acc += w2p[4*k+0]*fv.x + w2p[4*k+1]*fv.y + w2p[4*k+2]*fv.z + w2p[4*k+3]*fv.w;
      }
      psum[u * 512 + t * 64 + ln] = acc;
    }
    __syncthreads();
    {   // wave u owns token u: reduce + residual + LN + store
      float o2 = b2v;
      #pragma unroll
      for (int v = 0; v < 8; v++) o2 += psum[v * 512 + u * 64 + ln];
      float res = o2 + hid8[u][ln];
      float mu  = wave64_sum(res) * (1.f / 64.f);
      float dv  = res - mu;
      float var = wave64_sum(dv * dv) * (1.f / 64.f);
      out[((long)b * Ln + t0 + u) * Dm + ln] = dv * rsqrtf(var + 1e-12f) * fw + fb;
    }
    __syncthreads();
  }
}

extern "C" void kernel_launch(void* const* d_in, const int* in_sizes, int n_in,
                              void* d_out, int out_size, void* d_ws, size_t ws_size,
                              hipStream_t stream)
{
  const int*   ids  = (const int*)  d_in[0];
  const float* emb  = (const float*)d_in[1];
  const float* lnw  = (const float*)d_in[2];
  const float* lnb  = (const float*)d_in[3];
  const float* ipw  = (const float*)d_in[4];
  const float* cw   = (const float*)d_in[5];
  const float* cb   = (const float*)d_in[6];
  const float* xpw  = (const float*)d_in[7];
  const float* dtw  = (const float*)d_in[8];
  const float* dtb  = (const float*)d_in[9];
  const float* alog = (const float*)d_in[10];
  const float* Dp   = (const float*)d_in[11];
  const float* opw  = (const float*)d_in[12];
  const float* mlnw = (const float*)d_in[13];
  const float* mlnb = (const float*)d_in[14];
  const float* w1   = (const float*)d_in[15];
  const float* b1   = (const float*)d_in[16];
  const float* w2   = (const float*)d_in[17];
  const float* b2   = (const float*)d_in[18];
  const float* flnw = (const float*)d_in[19];
  const float* flnb = (const float*)d_in[20];
  float* out = (float*)d_out;

  const size_t half = (size_t)Bn * Ln * DI * sizeof(unsigned short);  // 52,428,800 B
  unsigned short* xc = (unsigned short*)d_ws;                         // [B,L,DI] bf16
  unsigned short* zy = (unsigned short*)((char*)d_ws + half);         // z, then y in-place

  k1_embed_inproj<<<Bn * 5, 256, 0, stream>>>(ids, emb, lnw, lnb, ipw, xc, zy);
  k2_conv_scan<<<Bn, 256, 0, stream>>>(xc, zy, cw, cb, xpw, dtw, dtb, alog, Dp);
  k3_out_ffn<<<Bn, 512, 0, stream>>>(zy, opw, mlnw, mlnb, w1, b1, w2, b2,
                                     flnw, flnb, out);
}

// Round 11
// 909.129 us; speedup vs baseline: 1.7067x; 1.7067x over previous
//
#include <hip/hip_runtime.h>
#include <hip/hip_bf16.h>

// Mamba4Rec fused forward. B=1024, L=200, D=64, DI=128, N=32, K=4, R=4, F=256.
constexpr int Bn = 1024, Ln = 200, Dm = 64, DI = 128, Fh = 256;

#define DEVFN __device__ __forceinline__

typedef __attribute__((ext_vector_type(8))) short bf16x8;
typedef __attribute__((ext_vector_type(4))) float f32x4;

DEVFN float silu_(float x){ return x / (1.f + __expf(-x)); }
DEVFN float softplus_(float x){ return x > 20.f ? x : log1pf(__expf(x)); }
DEVFN float gelu_tanh_(float x){
  float c = 0.7978845608028654f * (x + 0.044715f * x * x * x);
  float e = __expf(2.f * c);
  float th = 1.f - 2.f / (e + 1.f);
  return 0.5f * x * (1.f + th);
}
DEVFN float wave64_sum(float v){
  #pragma unroll
  for (int off = 32; off; off >>= 1) v += __shfl_xor(v, off, 64);
  return v;
}
DEVFN unsigned short f2b(float f){           // f32 -> bf16 RNE
  unsigned int u = __float_as_uint(f);
  return (unsigned short)((u + 0x7fffu + ((u >> 16) & 1u)) >> 16);
}
DEVFN float b2f(unsigned short h){ return __uint_as_float(((unsigned int)h) << 16); }

// ============ K1: embed + LN + in_proj -> xc (bf16), z (bf16) ============
__global__ __launch_bounds__(256)
void k1_embed_inproj(
    const int* __restrict__ ids, const float* __restrict__ emb,
    const float* __restrict__ lnw, const float* __restrict__ lnb,
    const float* __restrict__ ipw,
    unsigned short* __restrict__ xc, unsigned short* __restrict__ zy)
{
  __shared__ float xls[8][Dm];
  const int blk = blockIdx.x, b = blk / 5, t0 = (blk % 5) * 40;
  const int tid = threadIdx.x, wv = tid >> 6, ln = tid & 63;
  float wip[64];
  { const float4* p = (const float4*)(ipw + tid * Dm);
    #pragma unroll
    for (int k = 0; k < 16; k++) ((float4*)wip)[k] = p[k]; }
  const float lw = lnw[ln], lb = lnb[ln];
  const int* idb = ids + b * Ln;

  for (int sub = 0; sub < 5; sub++) {
    const int tt0 = t0 + sub * 8;
    #pragma unroll
    for (int s = 0; s < 2; s++) {
      int i = wv + 4 * s;
      float v = emb[(long)idb[tt0 + i] * Dm + ln];
      float mu  = wave64_sum(v) * (1.f / 64.f);
      float dv  = v - mu;
      float var = wave64_sum(dv * dv) * (1.f / 64.f);
      xls[i][ln] = dv * rsqrtf(var + 1e-12f) * lw + lb;
    }
    __syncthreads();
    #pragma unroll
    for (int i = 0; i < 8; i++) {
      const float4* xp = (const float4*)xls[i];
      float acc = 0.f;
      #pragma unroll
      for (int k = 0; k < 16; k++) {
        float4 x = xp[k];
        acc += wip[4*k+0]*x.x + wip[4*k+1]*x.y + wip[4*k+2]*x.z + wip[4*k+3]*x.w;
      }
      long idx = ((long)b * Ln + tt0 + i) * DI;
      unsigned short hv = f2b(acc);
      if (tid < DI) xc[idx + tid] = hv;
      else          zy[idx + tid - DI] = hv;
    }
    __syncthreads();
  }
}

// ============ K2: conv + SiLU + x_proj + dt_proj + scan + gate -> y (bf16, over z) ============
__global__ __launch_bounds__(256)
void k2_conv_scan(
    const unsigned short* __restrict__ xc, unsigned short* __restrict__ zy,
    const float* __restrict__ cw, const float* __restrict__ cb,
    const float* __restrict__ xpw, const float* __restrict__ dtw, const float* __restrict__ dtb,
    const float* __restrict__ A_log, const float* __restrict__ Dp_g)
{
  constexpr int T = 8;
  __shared__ float xct[T + 3][DI];
  __shared__ float xs_s[T][132];
  __shared__ unsigned short z_s[T][DI];
  __shared__ unsigned short y_s[T][DI];
  __shared__ float psum[4][64 * 9];
  __shared__ float bc_s[T][68];
  __shared__ float dtlo_s[T][4];
  __shared__ float xpw_ext[4][DI];

  const int b = blockIdx.x, tid = threadIdx.x;
  const int wv = tid >> 6, ln = tid & 63;

  float wxp[32];
  { const float4* p = (const float4*)(xpw + ln * DI + wv * 32);
    #pragma unroll
    for (int k = 0; k < 8; k++) ((float4*)wxp)[k] = p[k]; }
  const int cd = tid & (DI - 1);
  const float4 cwv = *(const float4*)(cw + cd * 4);
  const float cbv = cb[cd];
  const int sd = tid >> 1, hf = tid & 1;
  const float4 dtwv = *(const float4*)(dtw + sd * 4);
  const float dtbv = dtb[sd], Dpv = Dp_g[sd];
  float A[16];
  { const float4* p = (const float4*)(A_log + sd * 32 + hf * 16);
    #pragma unroll
    for (int k = 0; k < 4; k++) {
      float4 v = p[k];
      A[4*k+0] = -__expf(v.x); A[4*k+1] = -__expf(v.y);
      A[4*k+2] = -__expf(v.z); A[4*k+3] = -__expf(v.w);
    } }
  float h[16];
  #pragma unroll
  for (int k = 0; k < 16; k++) h[k] = 0.f;

  for (int i = tid; i < 4 * DI; i += 256) xpw_ext[i >> 7][i & 127] = xpw[64 * DI + i];
  for (int i = tid; i < 3 * DI; i += 256) xct[i >> 7][i & 127] = 0.f;
  __syncthreads();

  for (int tile = 0; tile < 25; ++tile) {
    const int t0 = tile * T;
    const long gbase = ((long)b * Ln + t0) * DI;
    {
      ushort4 xv = ((const ushort4*)(xc + gbase))[tid];
      ushort4 zv = ((const ushort4*)(zy + gbase))[tid];
      int row = tid >> 5, col = (tid & 31) * 4;
      xct[3 + row][col + 0] = b2f(xv.x); xct[3 + row][col + 1] = b2f(xv.y);
      xct[3 + row][col + 2] = b2f(xv.z); xct[3 + row][col + 3] = b2f(xv.w);
      ((ushort4*)z_s)[tid] = zv;
    }
    __syncthreads();
    #pragma unroll
    for (int s = 0; s < 4; s++) {
      int tt = (tid >> 7) + 2 * s;
      float v = cbv + cwv.x * xct[tt + 0][cd] + cwv.y * xct[tt + 1][cd]
                    + cwv.z * xct[tt + 2][cd] + cwv.w * xct[tt + 3][cd];
      xs_s[tt][cd] = silu_(v);
    }
    __syncthreads();
    #pragma unroll
    for (int t = 0; t < T; t++) {
      const float4* xr = (const float4*)(&xs_s[t][wv * 32]);
      float a = 0.f;
      #pragma unroll
      for (int k = 0; k < 8; k++) {
        float4 x = xr[k];
        a += wxp[4*k+0]*x.x + wxp[4*k+1]*x.y + wxp[4*k+2]*x.z + wxp[4*k+3]*x.w;
      }
      psum[wv][ln * 9 + t] = a;
    }
    if (tid < 32) {
      int j = tid >> 3, t = tid & 7;
      const float4* wr = (const float4*)xpw_ext[j];
      const float4* xr = (const float4*)(&xs_s[t][0]);
      float a = 0.f;
      #pragma unroll
      for (int k = 0; k < 32; k++) {
        float4 w4 = wr[k]; float4 x = xr[k];
        a += w4.x*x.x + w4.y*x.y + w4.z*x.z + w4.w*x.w;
      }
      bc_s[t][60 + j] = a;
    }
    __syncthreads();
    #pragma unroll
    for (int s = 0; s < 2; s++) {
      int o = tid + 256 * s;
      int j = o >> 3, t = o & 7;
      float sum = psum[0][j*9+t] + psum[1][j*9+t] + psum[2][j*9+t] + psum[3][j*9+t];
      if (j < 4) dtlo_s[t][j] = sum;
      else       bc_s[t][j - 4] = sum;
    }
    __syncthreads();
    for (int t = 0; t < T; t++) {
      float4 dl = *(const float4*)dtlo_s[t];
      float dtv = softplus_(dtwv.x*dl.x + dtwv.y*dl.y + dtwv.z*dl.z + dtwv.w*dl.w + dtbv);
      float xsv = xs_s[t][sd];
      float zv  = b2f(z_s[t][sd]);
      float du  = dtv * xsv;
      const float4* bp = (const float4*)(&bc_s[t][hf * 16]);
      const float4* cp = (const float4*)(&bc_s[t][32 + hf * 16]);
      float y = 0.f;
      #pragma unroll
      for (int k = 0; k < 4; k++) {
        float4 Bv = bp[k], Cv = cp[k];
        float h0 = __expf(dtv*A[4*k+0]) * h[4*k+0] + du * Bv.x; h[4*k+0] = h0; y += h0 * Cv.x;
        float h1 = __expf(dtv*A[4*k+1]) * h[4*k+1] + du * Bv.y; h[4*k+1] = h1; y += h1 * Cv.y;
        float h2 = __expf(dtv*A[4*k+2]) * h[4*k+2] + du * Bv.z; h[4*k+2] = h2; y += h2 * Cv.z;
        float h3 = __expf(dtv*A[4*k+3]) * h[4*k+3] + du * Bv.w; h[4*k+3] = h3; y += h3 * Cv.w;
      }
      float yo = y + __shfl_xor(y, 1, 64);
      if (hf == 0)
        y_s[t][sd] = f2b((yo + Dpv * xsv) * silu_(zv));
    }
    __syncthreads();
    ((ushort4*)(zy + gbase))[tid] = ((ushort4*)y_s)[tid];
    for (int i = tid; i < 3 * DI; i += 256)
      xct[i >> 7][i & 127] = xct[8 + (i >> 7)][i & 127];
    __syncthreads();
  }
}

// ============ K3a: out_proj (MFMA) + LN + ffn1 (MFMA) + GELU -> hid (bf16), f (bf16) ============
// grid 3200 x 256 thr (4 waves x 16 tokens). Weights staged as pre-swizzled bf16 B-frags in LDS.
// MFMA 16x16x32_bf16 layouts: A lane l: row m=l&15, k=(l>>4)*8+e; B: col n=l&15, same k.
// C/D: col=lane&15, row=(lane>>4)*4+reg  [verified mapping].
__global__ __launch_bounds__(256)
void k3a_op_ffn1(
    const unsigned short* __restrict__ y_g, const float* __restrict__ opw,
    const float* __restrict__ mlnw, const float* __restrict__ mlnb,
    const float* __restrict__ w1, const float* __restrict__ b1,
    unsigned short* __restrict__ hid_g, unsigned short* __restrict__ f_g)
{
  __shared__ unsigned short opwF[4][4][64][8];   // [nt][kc][lane][e]  16 KB
  __shared__ unsigned short w1F[16][2][64][8];   //                    32 KB
  __shared__ unsigned short hidT[4][16][72];     // per-wave, padded   9.2 KB
  __shared__ float mlnw_s[64], mlnb_s[64], b1_s[Fh];
  const int tid = threadIdx.x, l = tid & 63, w = tid >> 6;

  // stage out_proj B-frags: opwF[nt][kc][lane][e] = bf16(opw[nt*16+(lane&15)][kc*32+(lane>>4)*8+e])
  for (int i = tid; i < 1024; i += 256) {
    int lane = i & 63, kc = (i >> 6) & 3, nt = i >> 8;
    const float* src = opw + (nt*16 + (lane & 15)) * DI + kc*32 + (lane >> 4)*8;
    unsigned short* dst = &opwF[nt][kc][lane][0];
    #pragma unroll
    for (int e = 0; e < 8; e++) dst[e] = f2b(src[e]);
  }
  // stage ffn1 B-frags: w1F[nt][kc][lane][e] = bf16(w1[nt*16+(lane&15)][kc*32+(lane>>4)*8+e])
  for (int i = tid; i < 2048; i += 256) {
    int lane = i & 63, kc = (i >> 6) & 1, nt = i >> 7;
    const float* src = w1 + (nt*16 + (lane & 15)) * Dm + kc*32 + (lane >> 4)*8;
    unsigned short* dst = &w1F[nt][kc][lane][0];
    #pragma unroll
    for (int e = 0; e < 8; e++) dst[e] = f2b(src[e]);
  }
  if (tid < 64) { mlnw_s[tid] = mlnw[tid]; mlnb_s[tid] = mlnb[tid]; }
  b1_s[tid] = b1[tid];
  __syncthreads();

  const long tok0 = (long)blockIdx.x * 64 + w * 16;
  const int m = l & 15, kg = l >> 4;

  // ---- out_proj: [16 x 128] @ [128 x 64] ----
  bf16x8 ya[4];
  { const unsigned short* yp = y_g + (tok0 + m) * DI + kg * 8;
    #pragma unroll
    for (int kc = 0; kc < 4; kc++) ya[kc] = *(const bf16x8*)(yp + kc * 32); }
  f32x4 acc[4];
  #pragma unroll
  for (int nt = 0; nt < 4; nt++) {
    f32x4 a = {0.f, 0.f, 0.f, 0.f};
    #pragma unroll
    for (int kc = 0; kc < 4; kc++)
      a = __builtin_amdgcn_mfma_f32_16x16x32_bf16(ya[kc], *(const bf16x8*)&opwF[nt][kc][l][0], a, 0, 0, 0);
    acc[nt] = a;
  }
  // ---- in-register LN over 64 features (16-lane groups, 4 tokens per lane) ----
  float mu[4], rs[4];
  #pragma unroll
  for (int r = 0; r < 4; r++) {
    float s = acc[0][r] + acc[1][r] + acc[2][r] + acc[3][r];
    #pragma unroll
    for (int off = 1; off < 16; off <<= 1) s += __shfl_xor(s, off, 64);
    mu[r] = s * (1.f / 64.f);
  }
  #pragma unroll
  for (int r = 0; r < 4; r++) {
    float q = 0.f;
    #pragma unroll
    for (int nt = 0; nt < 4; nt++) { float d = acc[nt][r] - mu[r]; q += d * d; }
    #pragma unroll
    for (int off = 1; off < 16; off <<= 1) q += __shfl_xor(q, off, 64);
    rs[r] = rsqrtf(q * (1.f / 64.f) + 1e-12f);
  }
  #pragma unroll
  for (int nt = 0; nt < 4; nt++) {
    int n = nt * 16 + (l & 15);
    float mwv = mlnw_s[n], mbv = mlnb_s[n];
    #pragma unroll
    for (int r = 0; r < 4; r++) {
      int mm = (l >> 4) * 4 + r;
      unsigned short hb = f2b((acc[nt][r] - mu[r]) * rs[r] * mwv + mbv);
      hidT[w][mm][n] = hb;
      hid_g[(tok0 + mm) * Dm + n] = hb;
    }
  }
  // ---- ffn1: [16 x 64] @ [64 x 256], + bias + GELU -> f_g ----
  bf16x8 ha[2];
  #pragma unroll
  for (int kc = 0; kc < 2; kc++)
    ha[kc] = *(const bf16x8*)&hidT[w][m][kc * 32 + kg * 8];
  #pragma unroll
  for (int nt = 0; nt < 16; nt++) {
    f32x4 a = {0.f, 0.f, 0.f, 0.f};
    a = __builtin_amdgcn_mfma_f32_16x16x32_bf16(ha[0], *(const bf16x8*)&w1F[nt][0][l][0], a, 0, 0, 0);
    a = __builtin_amdgcn_mfma_f32_16x16x32_bf16(ha[1], *(const bf16x8*)&w1F[nt][1][l][0], a, 0, 0, 0);
    int n = nt * 16 + (l & 15);
    float bv = b1_s[n];
    #pragma unroll
    for (int r = 0; r < 4; r++) {
      int mm = (l >> 4) * 4 + r;
      f_g[(tok0 + mm) * Fh + n] = f2b(gelu_tanh_(a[r] + bv));
    }
  }
}

// ============ K3b: ffn2 (MFMA) + bias + residual + LN -> out (f32) ============
__global__ __launch_bounds__(256)
void k3b_ffn2(
    const unsigned short* __restrict__ f_g, const unsigned short* __restrict__ hid_g,
    const float* __restrict__ w2, const float* __restrict__ b2,
    const float* __restrict__ flnw, const float* __restrict__ flnb,
    float* __restrict__ out)
{
  __shared__ unsigned short w2F[4][8][64][8];   // [nt][kc][lane][e]  32 KB
  __shared__ float b2_s[64], flw_s[64], flb_s[64];
  const int tid = threadIdx.x, l = tid & 63, w = tid >> 6;

  for (int i = tid; i < 2048; i += 256) {
    int lane = i & 63, kc = (i >> 6) & 7, nt = i >> 9;
    const float* src = w2 + (nt*16 + (lane & 15)) * Fh + kc*32 + (lane >> 4)*8;
    unsigned short* dst = &w2F[nt][kc][lane][0];
    #pragma unroll
    for (int e = 0; e < 8; e++) dst[e] = f2b(src[e]);
  }
  if (tid < 64) { b2_s[tid] = b2[tid]; flw_s[tid] = flnw[tid]; flb_s[tid] = flnb[tid]; }
  __syncthreads();

  const long tok0 = (long)blockIdx.x * 64 + w * 16;
  const int m = l & 15, kg = l >> 4;

  // ---- ffn2: [16 x 256] @ [256 x 64] ----
  bf16x8 fa[8];
  { const unsigned short* fp = f_g + (tok0 + m) * Fh + kg * 8;
    #pragma unroll
    for (int kc = 0; kc < 8; kc++) fa[kc] = *(const bf16x8*)(fp + kc * 32); }
  f32x4 acc[4];
  #pragma unroll
  for (int nt = 0; nt < 4; nt++) {
    f32x4 a = {0.f, 0.f, 0.f, 0.f};
    #pragma unroll
    for (int kc = 0; kc < 8; kc++)
      a = __builtin_amdgcn_mfma_f32_16x16x32_bf16(fa[kc], *(const bf16x8*)&w2F[nt][kc][l][0], a, 0, 0, 0);
    acc[nt] = a;
  }
  // ---- + bias + residual(hid) ----
  #pragma unroll
  for (int nt = 0; nt < 4; nt++) {
    int n = nt * 16 + (l & 15);
    float bv = b2_s[n];
    #pragma unroll
    for (int r = 0; r < 4; r++) {
      int mm = (l >> 4) * 4 + r;
      acc[nt][r] += bv + b2f(hid_g[(tok0 + mm) * Dm + n]);
    }
  }
  // ---- in-register LN -> out ----
  float mu[4], rs[4];
  #pragma unroll
  for (int r = 0; r < 4; r++) {
    float s = acc[0][r] + acc[1][r] + acc[2][r] + acc[3][r];
    #pragma unroll
    for (int off = 1; off < 16; off <<= 1) s += __shfl_xor(s, off, 64);
    mu[r] = s * (1.f / 64.f);
  }
  #pragma unroll
  for (int r = 0; r < 4; r++) {
    float q = 0.f;
    #pragma unroll
    for (int nt = 0; nt < 4; nt++) { float d = acc[nt][r] - mu[r]; q += d * d; }
    #pragma unroll
    for (int off = 1; off < 16; off <<= 1) q += __shfl_xor(q, off, 64);
    rs[r] = rsqrtf(q * (1.f / 64.f) + 1e-12f);
  }
  #pragma unroll
  for (int nt = 0; nt < 4; nt++) {
    int n = nt * 16 + (l & 15);
    float fwv = flw_s[n], fbv = flb_s[n];
    #pragma unroll
    for (int r = 0; r < 4; r++) {
      int mm = (l >> 4) * 4 + r;
      out[(tok0 + mm) * Dm + n] = (acc[nt][r] - mu[r]) * rs[r] * fwv + fbv;
    }
  }
}

extern "C" void kernel_launch(void* const* d_in, const int* in_sizes, int n_in,
                              void* d_out, int out_size, void* d_ws, size_t ws_size,
                              hipStream_t stream)
{
  const int*   ids  = (const int*)  d_in[0];
  const float* emb  = (const float*)d_in[1];
  const float* lnw  = (const float*)d_in[2];
  const float* lnb  = (const float*)d_in[3];
  const float* ipw  = (const float*)d_in[4];
  const float* cw   = (const float*)d_in[5];
  const float* cb   = (const float*)d_in[6];
  const float* xpw  = (const float*)d_in[7];
  const float* dtw  = (const float*)d_in[8];
  const float* dtb  = (const float*)d_in[9];
  const float* alog = (const float*)d_in[10];
  const float* Dp   = (const float*)d_in[11];
  const float* opw  = (const float*)d_in[12];
  const float* mlnw = (const float*)d_in[13];
  const float* mlnb = (const float*)d_in[14];
  const float* w1   = (const float*)d_in[15];
  const float* b1   = (const float*)d_in[16];
  const float* w2   = (const float*)d_in[17];
  const float* b2   = (const float*)d_in[18];
  const float* flnw = (const float*)d_in[19];
  const float* flnb = (const float*)d_in[20];
  float* out = (float*)d_out;

  const size_t half = (size_t)Bn * Ln * DI * sizeof(unsigned short);  // 52,428,800 B
  char* ws = (char*)d_ws;
  unsigned short* xc   = (unsigned short*)ws;                 // [M][128] bf16 (k1->k2)
  unsigned short* zy   = (unsigned short*)(ws + half);        // z then y in place (k1->k2->k3a)
  unsigned short* hid  = (unsigned short*)ws;                 // [M][64] bf16, aliases dead xc (k3a->k3b)
  unsigned short* fact = (unsigned short*)(ws + 2 * half);    // [M][256] bf16, 100 MB (k3a->k3b)
  // total workspace footprint: 200 MB

  k1_embed_inproj<<<Bn * 5, 256, 0, stream>>>(ids, emb, lnw, lnb, ipw, xc, zy);
  k2_conv_scan<<<Bn, 256, 0, stream>>>(xc, zy, cw, cb, xpw, dtw, dtb, alog, Dp);
  k3a_op_ffn1<<<(Bn * Ln) / 64, 256, 0, stream>>>(zy, opw, mlnw, mlnb, w1, b1, hid, fact);
  k3b_ffn2<<<(Bn * Ln) / 64, 256, 0, stream>>>(fact, hid, w2, b2, flnw, flnb, out);
}

// Round 15
// 791.634 us; speedup vs baseline: 1.9600x; 1.1484x over previous
//
#include <hip/hip_runtime.h>
#include <hip/hip_bf16.h>

// Mamba4Rec fused forward. B=1024, L=200, D=64, DI=128, N=32, K=4, R=4, F=256.
constexpr int Bn = 1024, Ln = 200, Dm = 64, DI = 128, Fh = 256;

#define DEVFN __device__ __forceinline__

typedef __attribute__((ext_vector_type(8))) short bf16x8;
typedef __attribute__((ext_vector_type(4))) float f32x4;

DEVFN float silu_(float x){ return x / (1.f + __expf(-x)); }
DEVFN float softplus_(float x){ return x > 20.f ? x : log1pf(__expf(x)); }
DEVFN float gelu_tanh_(float x){
  float c = 0.7978845608028654f * (x + 0.044715f * x * x * x);
  float e = __expf(2.f * c);
  float th = 1.f - 2.f / (e + 1.f);
  return 0.5f * x * (1.f + th);
}
DEVFN float wave64_sum(float v){
  #pragma unroll
  for (int off = 32; off; off >>= 1) v += __shfl_xor(v, off, 64);
  return v;
}
DEVFN unsigned short f2b(float f){           // f32 -> bf16 RNE
  unsigned int u = __float_as_uint(f);
  return (unsigned short)((u + 0x7fffu + ((u >> 16) & 1u)) >> 16);
}
DEVFN float b2f(unsigned short h){ return __uint_as_float(((unsigned int)h) << 16); }

// ============ K1: embed + LN + in_proj -> xc (bf16), z (bf16) ============
__global__ __launch_bounds__(256)
void k1_embed_inproj(
    const int* __restrict__ ids, const float* __restrict__ emb,
    const float* __restrict__ lnw, const float* __restrict__ lnb,
    const float* __restrict__ ipw,
    unsigned short* __restrict__ xc, unsigned short* __restrict__ zy)
{
  __shared__ float xls[8][Dm];
  const int blk = blockIdx.x, b = blk / 5, t0 = (blk % 5) * 40;
  const int tid = threadIdx.x, wv = tid >> 6, ln = tid & 63;
  float wip[64];
  { const float4* p = (const float4*)(ipw + tid * Dm);
    #pragma unroll
    for (int k = 0; k < 16; k++) ((float4*)wip)[k] = p[k]; }
  const float lw = lnw[ln], lb = lnb[ln];
  const int* idb = ids + b * Ln;

  for (int sub = 0; sub < 5; sub++) {
    const int tt0 = t0 + sub * 8;
    #pragma unroll
    for (int s = 0; s < 2; s++) {
      int i = wv + 4 * s;
      float v = emb[(long)idb[tt0 + i] * Dm + ln];
      float mu  = wave64_sum(v) * (1.f / 64.f);
      float dv  = v - mu;
      float var = wave64_sum(dv * dv) * (1.f / 64.f);
      xls[i][ln] = dv * rsqrtf(var + 1e-12f) * lw + lb;
    }
    __syncthreads();
    #pragma unroll
    for (int i = 0; i < 8; i++) {
      const float4* xp = (const float4*)xls[i];
      float acc = 0.f;
      #pragma unroll
      for (int k = 0; k < 16; k++) {
        float4 x = xp[k];
        acc += wip[4*k+0]*x.x + wip[4*k+1]*x.y + wip[4*k+2]*x.z + wip[4*k+3]*x.w;
      }
      long idx = ((long)b * Ln + tt0 + i) * DI;
      unsigned short hv = f2b(acc);
      if (tid < DI) xc[idx + tid] = hv;
      else          zy[idx + tid - DI] = hv;
    }
    __syncthreads();
  }
}

// ============ K2a: depthwise conv + SiLU + x_proj (MFMA) -> xs(bf16), dtlo(f32), bc(bf16) ============
// grid 3200 x 256 (4 waves x 16 tokens). 64-token flat tiles cross sequence boundaries;
// conv masks terms with in-sequence position p-3+j < 0.
__global__ __launch_bounds__(256)
void k2a_conv_xproj(
    const unsigned short* __restrict__ xc,
    const float* __restrict__ cw, const float* __restrict__ cb,
    const float* __restrict__ xpw,
    unsigned short* __restrict__ xs_g, float* __restrict__ dtlo_g,
    unsigned short* __restrict__ bc_g)
{
  __shared__ unsigned short xctS[67 * 128];      // halo tile, row-major    17.2 KB
  __shared__ unsigned short xsS[64 * 144];       // padded for A-frag reads 18.4 KB
  __shared__ unsigned short xpwF[5][4][64][8];   // x_proj B-frags          20.5 KB
  const int tid = threadIdx.x, l = tid & 63, w = tid >> 6;
  const long tok0 = (long)blockIdx.x * 64;

  // stage x_proj B-frags: row n = nt*16+(l&15) (pad rows >=68 with 0)
  for (int i = tid; i < 1280; i += 256) {
    int lane = i & 63, kc = (i >> 6) & 3, nt = i >> 8;
    int row = nt * 16 + (lane & 15);
    unsigned short* dst = &xpwF[nt][kc][lane][0];
    if (row < 68) {
      const float* src = xpw + row * DI + kc * 32 + (lane >> 4) * 8;
      #pragma unroll
      for (int e = 0; e < 8; e++) dst[e] = f2b(src[e]);
    } else {
      #pragma unroll
      for (int e = 0; e < 8; e++) dst[e] = 0;
    }
  }
  // stage xc rows tok0-3 .. tok0+63 (ft<0 -> 0)
  for (int i = tid; i < 67 * 32; i += 256) {
    int rr = i >> 5, c4 = i & 31;
    long ft = tok0 - 3 + rr;
    ushort4 v;
    if (ft >= 0) v = ((const ushort4*)(xc + ft * DI))[c4];
    else { v.x = 0; v.y = 0; v.z = 0; v.w = 0; }
    ((ushort4*)xctS)[rr * 32 + c4] = v;
  }
  __syncthreads();

  // conv + SiLU: thread owns 4 channels d4..d4+3, iterates 8 token rows
  {
    const int d4 = (tid & 31) * 4;
    const int base200 = (int)(tok0 % 200);
    float4 cv[4]; float cbr[4];
    #pragma unroll
    for (int c = 0; c < 4; c++) { cv[c] = *(const float4*)(cw + (d4 + c) * 4); cbr[c] = cb[d4 + c]; }
    for (int t = tid >> 5; t < 64; t += 8) {
      int p = base200 + t; if (p >= 200) p -= 200;
      ushort4 r0 = *(const ushort4*)&xctS[(t + 0) * 128 + d4];
      ushort4 r1 = *(const ushort4*)&xctS[(t + 1) * 128 + d4];
      ushort4 r2 = *(const ushort4*)&xctS[(t + 2) * 128 + d4];
      ushort4 r3 = *(const ushort4*)&xctS[(t + 3) * 128 + d4];
      float m0 = (p >= 3) ? 1.f : 0.f, m1 = (p >= 2) ? 1.f : 0.f, m2 = (p >= 1) ? 1.f : 0.f;
      ushort4 o;
      { float a = cbr[0] + m0*cv[0].x*b2f(r0.x) + m1*cv[0].y*b2f(r1.x) + m2*cv[0].z*b2f(r2.x) + cv[0].w*b2f(r3.x); o.x = f2b(silu_(a)); }
      { float a = cbr[1] + m0*cv[1].x*b2f(r0.y) + m1*cv[1].y*b2f(r1.y) + m2*cv[1].z*b2f(r2.y) + cv[1].w*b2f(r3.y); o.y = f2b(silu_(a)); }
      { float a = cbr[2] + m0*cv[2].x*b2f(r0.z) + m1*cv[2].y*b2f(r1.z) + m2*cv[2].z*b2f(r2.z) + cv[2].w*b2f(r3.z); o.z = f2b(silu_(a)); }
      { float a = cbr[3] + m0*cv[3].x*b2f(r0.w) + m1*cv[3].y*b2f(r1.w) + m2*cv[3].z*b2f(r2.w) + cv[3].w*b2f(r3.w); o.w = f2b(silu_(a)); }
      *(ushort4*)&xsS[t * 144 + d4] = o;
      *(ushort4*)(xs_g + (tok0 + t) * DI + d4) = o;
    }
  }
  __syncthreads();

  // x_proj MFMA: per wave [16 x 128] @ [128 x 80(68)]
  {
    const int m = l & 15, kg = l >> 4;
    const int tr = w * 16 + m;
    bf16x8 xa[4];
    #pragma unroll
    for (int kc = 0; kc < 4; kc++)
      xa[kc] = *(const bf16x8*)&xsS[tr * 144 + kc * 32 + kg * 8];
    #pragma unroll
    for (int nt = 0; nt < 5; nt++) {
      f32x4 a = {0.f, 0.f, 0.f, 0.f};
      #pragma unroll
      for (int kc = 0; kc < 4; kc++)
        a = __builtin_amdgcn_mfma_f32_16x16x32_bf16(xa[kc], *(const bf16x8*)&xpwF[nt][kc][l][0], a, 0, 0, 0);
      int j = nt * 16 + m;   // output col
      #pragma unroll
      for (int r = 0; r < 4; r++) {
        long mm = tok0 + w * 16 + (l >> 4) * 4 + r;
        if (j < 4)       dtlo_g[mm * 4 + j] = a[r];
        else if (j < 68) bc_g[mm * 64 + (j - 4)] = f2b(a[r]);
      }
    }
  }
}

// ============ K2b: lean selective scan (+dt_proj+softplus, +D*xs, *silu(z)) -> y over z ============
// grid 1024 (one block per sequence), 256 threads (2 per channel), ~11.6 KB LDS.
__global__ __launch_bounds__(256)
void k2b_scan(
    const unsigned short* __restrict__ xs_g, unsigned short* __restrict__ zy,
    const unsigned short* __restrict__ bc_g, const float* __restrict__ dtlo_g,
    const float* __restrict__ dtw, const float* __restrict__ dtb,
    const float* __restrict__ A_log, const float* __restrict__ Dp_g)
{
  constexpr int T = 8;
  __shared__ unsigned short xs_s[T][DI];
  __shared__ unsigned short z_s[T][DI];
  __shared__ unsigned short y_s[T][DI];
  __shared__ float bc_s[T][68];
  __shared__ float dtlo_s[Ln][4];

  const int b = blockIdx.x, tid = threadIdx.x;
  const int sd = tid >> 1, hf = tid & 1;
  const float4 dtwv = *(const float4*)(dtw + sd * 4);
  const float dtbv = dtb[sd], Dpv = Dp_g[sd];
  float A[16];
  { const float4* p = (const float4*)(A_log + sd * 32 + hf * 16);
    #pragma unroll
    for (int k = 0; k < 4; k++) {
      float4 v = p[k];
      A[4*k+0] = -__expf(v.x); A[4*k+1] = -__expf(v.y);
      A[4*k+2] = -__expf(v.z); A[4*k+3] = -__expf(v.w);
    } }
  float h[16];
  #pragma unroll
  for (int k = 0; k < 16; k++) h[k] = 0.f;

  { const float4* src = (const float4*)(dtlo_g + (long)b * Ln * 4);
    float4* dst = (float4*)dtlo_s;
    for (int i = tid; i < Ln; i += 256) dst[i] = src[i]; }

  for (int tile = 0; tile < 25; ++tile) {
    const int t0 = tile * T;
    const long gbase = ((long)b * Ln + t0) * DI;
    ((ushort4*)xs_s)[tid] = ((const ushort4*)(xs_g + gbase))[tid];
    ((ushort4*)z_s)[tid]  = ((const ushort4*)(zy + gbase))[tid];
    if (tid < 128) {
      int t = tid >> 4, c4 = (tid & 15) * 4;
      ushort4 v = ((const ushort4*)(bc_g + ((long)b * Ln + t0) * 64))[tid];
      bc_s[t][c4 + 0] = b2f(v.x); bc_s[t][c4 + 1] = b2f(v.y);
      bc_s[t][c4 + 2] = b2f(v.z); bc_s[t][c4 + 3] = b2f(v.w);
    }
    __syncthreads();
    for (int t = 0; t < T; t++) {
      float4 dl = *(const float4*)dtlo_s[t0 + t];
      float dtv = softplus_(dtwv.x*dl.x + dtwv.y*dl.y + dtwv.z*dl.z + dtwv.w*dl.w + dtbv);
      float xsv = b2f(xs_s[t][sd]);
      float zv  = b2f(z_s[t][sd]);
      float du  = dtv * xsv;
      const float4* bp = (const float4*)(&bc_s[t][hf * 16]);
      const float4* cp = (const float4*)(&bc_s[t][32 + hf * 16]);
      float y = 0.f;
      #pragma unroll
      for (int k = 0; k < 4; k++) {
        float4 Bv = bp[k], Cv = cp[k];
        float h0 = __expf(dtv*A[4*k+0]) * h[4*k+0] + du * Bv.x; h[4*k+0] = h0; y += h0 * Cv.x;
        float h1 = __expf(dtv*A[4*k+1]) * h[4*k+1] + du * Bv.y; h[4*k+1] = h1; y += h1 * Cv.y;
        float h2 = __expf(dtv*A[4*k+2]) * h[4*k+2] + du * Bv.z; h[4*k+2] = h2; y += h2 * Cv.z;
        float h3 = __expf(dtv*A[4*k+3]) * h[4*k+3] + du * Bv.w; h[4*k+3] = h3; y += h3 * Cv.w;
      }
      float yo = y + __shfl_xor(y, 1, 64);
      if (hf == 0)
        y_s[t][sd] = f2b((yo + Dpv * xsv) * silu_(zv));
    }
    __syncthreads();
    ((ushort4*)(zy + gbase))[tid] = ((ushort4*)y_s)[tid];
  }
}

// ============ K3a: out_proj (MFMA) + LN + ffn1 (MFMA) + GELU -> hid (bf16), f (bf16) ============
__global__ __launch_bounds__(256)
void k3a_op_ffn1(
    const unsigned short* __restrict__ y_g, const float* __restrict__ opw,
    const float* __restrict__ mlnw, const float* __restrict__ mlnb,
    const float* __restrict__ w1, const float* __restrict__ b1,
    unsigned short* __restrict__ hid_g, unsigned short* __restrict__ f_g)
{
  __shared__ unsigned short opwF[4][4][64][8];
  __shared__ unsigned short w1F[16][2][64][8];
  __shared__ unsigned short hidT[4][16][72];
  __shared__ float mlnw_s[64], mlnb_s[64], b1_s[Fh];
  const int tid = threadIdx.x, l = tid & 63, w = tid >> 6;

  for (int i = tid; i < 1024; i += 256) {
    int lane = i & 63, kc = (i >> 6) & 3, nt = i >> 8;
    const float* src = opw + (nt*16 + (lane & 15)) * DI + kc*32 + (lane >> 4)*8;
    unsigned short* dst = &opwF[nt][kc][lane][0];
    #pragma unroll
    for (int e = 0; e < 8; e++) dst[e] = f2b(src[e]);
  }
  for (int i = tid; i < 2048; i += 256) {
    int lane = i & 63, kc = (i >> 6) & 1, nt = i >> 7;
    const float* src = w1 + (nt*16 + (lane & 15)) * Dm + kc*32 + (lane >> 4)*8;
    unsigned short* dst = &w1F[nt][kc][lane][0];
    #pragma unroll
    for (int e = 0; e < 8; e++) dst[e] = f2b(src[e]);
  }
  if (tid < 64) { mlnw_s[tid] = mlnw[tid]; mlnb_s[tid] = mlnb[tid]; }
  b1_s[tid] = b1[tid];
  __syncthreads();

  const long tok0 = (long)blockIdx.x * 64 + w * 16;
  const int m = l & 15, kg = l >> 4;

  bf16x8 ya[4];
  { const unsigned short* yp = y_g + (tok0 + m) * DI + kg * 8;
    #pragma unroll
    for (int kc = 0; kc < 4; kc++) ya[kc] = *(const bf16x8*)(yp + kc * 32); }
  f32x4 acc[4];
  #pragma unroll
  for (int nt = 0; nt < 4; nt++) {
    f32x4 a = {0.f, 0.f, 0.f, 0.f};
    #pragma unroll
    for (int kc = 0; kc < 4; kc++)
      a = __builtin_amdgcn_mfma_f32_16x16x32_bf16(ya[kc], *(const bf16x8*)&opwF[nt][kc][l][0], a, 0, 0, 0);
    acc[nt] = a;
  }
  float mu[4], rs[4];
  #pragma unroll
  for (int r = 0; r < 4; r++) {
    float s = acc[0][r] + acc[1][r] + acc[2][r] + acc[3][r];
    #pragma unroll
    for (int off = 1; off < 16; off <<= 1) s += __shfl_xor(s, off, 64);
    mu[r] = s * (1.f / 64.f);
  }
  #pragma unroll
  for (int r = 0; r < 4; r++) {
    float q = 0.f;
    #pragma unroll
    for (int nt = 0; nt < 4; nt++) { float d = acc[nt][r] - mu[r]; q += d * d; }
    #pragma unroll
    for (int off = 1; off < 16; off <<= 1) q += __shfl_xor(q, off, 64);
    rs[r] = rsqrtf(q * (1.f / 64.f) + 1e-12f);
  }
  #pragma unroll
  for (int nt = 0; nt < 4; nt++) {
    int n = nt * 16 + (l & 15);
    float mwv = mlnw_s[n], mbv = mlnb_s[n];
    #pragma unroll
    for (int r = 0; r < 4; r++) {
      int mm = (l >> 4) * 4 + r;
      unsigned short hb = f2b((acc[nt][r] - mu[r]) * rs[r] * mwv + mbv);
      hidT[w][mm][n] = hb;
      hid_g[(tok0 + mm) * Dm + n] = hb;
    }
  }
  bf16x8 ha[2];
  #pragma unroll
  for (int kc = 0; kc < 2; kc++)
    ha[kc] = *(const bf16x8*)&hidT[w][m][kc * 32 + kg * 8];
  #pragma unroll
  for (int nt = 0; nt < 16; nt++) {
    f32x4 a = {0.f, 0.f, 0.f, 0.f};
    a = __builtin_amdgcn_mfma_f32_16x16x32_bf16(ha[0], *(const bf16x8*)&w1F[nt][0][l][0], a, 0, 0, 0);
    a = __builtin_amdgcn_mfma_f32_16x16x32_bf16(ha[1], *(const bf16x8*)&w1F[nt][1][l][0], a, 0, 0, 0);
    int n = nt * 16 + (l & 15);
    float bv = b1_s[n];
    #pragma unroll
    for (int r = 0; r < 4; r++) {
      int mm = (l >> 4) * 4 + r;
      f_g[(tok0 + mm) * Fh + n] = f2b(gelu_tanh_(a[r] + bv));
    }
  }
}

// ============ K3b: ffn2 (MFMA) + bias + residual + LN -> out (f32) ============
__global__ __launch_bounds__(256)
void k3b_ffn2(
    const unsigned short* __restrict__ f_g, const unsigned short* __restrict__ hid_g,
    const float* __restrict__ w2, const float* __restrict__ b2,
    const float* __restrict__ flnw, const float* __restrict__ flnb,
    float* __restrict__ out)
{
  __shared__ unsigned short w2F[4][8][64][8];
  __shared__ float b2_s[64], flw_s[64], flb_s[64];
  const int tid = threadIdx.x, l = tid & 63, w = tid >> 6;

  for (int i = tid; i < 2048; i += 256) {
    int lane = i & 63, kc = (i >> 6) & 7, nt = i >> 9;
    const float* src = w2 + (nt*16 + (lane & 15)) * Fh + kc*32 + (lane >> 4)*8;
    unsigned short* dst = &w2F[nt][kc][lane][0];
    #pragma unroll
    for (int e = 0; e < 8; e++) dst[e] = f2b(src[e]);
  }
  if (tid < 64) { b2_s[tid] = b2[tid]; flw_s[tid] = flnw[tid]; flb_s[tid] = flnb[tid]; }
  __syncthreads();

  const long tok0 = (long)blockIdx.x * 64 + w * 16;
  const int m = l & 15, kg = l >> 4;

  bf16x8 fa[8];
  { const unsigned short* fp = f_g + (tok0 + m) * Fh + kg * 8;
    #pragma unroll
    for (int kc = 0; kc < 8; kc++) fa[kc] = *(const bf16x8*)(fp + kc * 32); }
  f32x4 acc[4];
  #pragma unroll
  for (int nt = 0; nt < 4; nt++) {
    f32x4 a = {0.f, 0.f, 0.f, 0.f};
    #pragma unroll
    for (int kc = 0; kc < 8; kc++)
      a = __builtin_amdgcn_mfma_f32_16x16x32_bf16(fa[kc], *(const bf16x8*)&w2F[nt][kc][l][0], a, 0, 0, 0);
    acc[nt] = a;
  }
  #pragma unroll
  for (int nt = 0; nt < 4; nt++) {
    int n = nt * 16 + (l & 15);
    float bv = b2_s[n];
    #pragma unroll
    for (int r = 0; r < 4; r++) {
      int mm = (l >> 4) * 4 + r;
      acc[nt][r] += bv + b2f(hid_g[(tok0 + mm) * Dm + n]);
    }
  }
  float mu[4], rs[4];
  #pragma unroll
  for (int r = 0; r < 4; r++) {
    float s = acc[0][r] + acc[1][r] + acc[2][r] + acc[3][r];
    #pragma unroll
    for (int off = 1; off < 16; off <<= 1) s += __shfl_xor(s, off, 64);
    mu[r] = s * (1.f / 64.f);
  }
  #pragma unroll
  for (int r = 0; r < 4; r++) {
    float q = 0.f;
    #pragma unroll
    for (int nt = 0; nt < 4; nt++) { float d = acc[nt][r] - mu[r]; q += d * d; }
    #pragma unroll
    for (int off = 1; off < 16; off <<= 1) q += __shfl_xor(q, off, 64);
    rs[r] = rsqrtf(q * (1.f / 64.f) + 1e-12f);
  }
  #pragma unroll
  for (int nt = 0; nt < 4; nt++) {
    int n = nt * 16 + (l & 15);
    float fwv = flw_s[n], fbv = flb_s[n];
    #pragma unroll
    for (int r = 0; r < 4; r++) {
      int mm = (l >> 4) * 4 + r;
      out[(tok0 + mm) * Dm + n] = (acc[nt][r] - mu[r]) * rs[r] * fwv + fbv;
    }
  }
}

extern "C" void kernel_launch(void* const* d_in, const int* in_sizes, int n_in,
                              void* d_out, int out_size, void* d_ws, size_t ws_size,
                              hipStream_t stream)
{
  const int*   ids  = (const int*)  d_in[0];
  const float* emb  = (const float*)d_in[1];
  const float* lnw  = (const float*)d_in[2];
  const float* lnb  = (const float*)d_in[3];
  const float* ipw  = (const float*)d_in[4];
  const float* cw   = (const float*)d_in[5];
  const float* cb   = (const float*)d_in[6];
  const float* xpw  = (const float*)d_in[7];
  const float* dtw  = (const float*)d_in[8];
  const float* dtb  = (const float*)d_in[9];
  const float* alog = (const float*)d_in[10];
  const float* Dp   = (const float*)d_in[11];
  const float* opw  = (const float*)d_in[12];
  const float* mlnw = (const float*)d_in[13];
  const float* mlnb = (const float*)d_in[14];
  const float* w1   = (const float*)d_in[15];
  const float* b1   = (const float*)d_in[16];
  const float* w2   = (const float*)d_in[17];
  const float* b2   = (const float*)d_in[18];
  const float* flnw = (const float*)d_in[19];
  const float* flnb = (const float*)d_in[20];
  float* out = (float*)d_out;

  const size_t half = (size_t)Bn * Ln * DI * sizeof(unsigned short);   // 52,428,800 B
  const long M = (long)Bn * Ln;
  char* ws = (char*)d_ws;
  unsigned short* xc   = (unsigned short*)ws;                     // [M,128] (k1->k2a)
  unsigned short* zy   = (unsigned short*)(ws + half);            // z -> y in place (k1->k2b->k3a)
  unsigned short* xs   = (unsigned short*)(ws + 2 * half);        // [M,128] (k2a->k2b)
  unsigned short* bc   = (unsigned short*)(ws + 3 * half);        // [M,64] bf16, 26.2 MB (k2a->k2b)
  float*          dtlo = (float*)(ws + 3 * half + M * 64 * 2);    // [M,4] f32, 3.3 MB
  unsigned short* hid  = (unsigned short*)ws;                     // aliases dead xc (k3a->k3b)
  unsigned short* fact = (unsigned short*)(ws + 2 * half);        // [M,256] bf16, aliases dead xs+bc
  // peak footprint: 3*half + 29.5 MB ≈ 179 MB (within proven 200 MB envelope)

  k1_embed_inproj<<<Bn * 5, 256, 0, stream>>>(ids, emb, lnw, lnb, ipw, xc, zy);
  k2a_conv_xproj<<<(int)(M / 64), 256, 0, stream>>>(xc, cw, cb, xpw, xs, dtlo, bc);
  k2b_scan<<<Bn, 256, 0, stream>>>(xs, zy, bc, dtlo, dtw, dtb, alog, Dp);
  k3a_op_ffn1<<<(int)(M / 64), 256, 0, stream>>>(zy, opw, mlnw, mlnb, w1, b1, hid, fact);
  k3b_ffn2<<<(int)(M / 64), 256, 0, stream>>>(fact, hid, w2, b2, flnw, flnb, out);
}